// Round 1
// baseline (1896.002 us; speedup 1.0000x reference)
//
#include <hip/hip_runtime.h>
#include <hip/hip_bf16.h>

#define B_ 2
#define C_ 256
#define H_ 128
#define W_ 128
#define HW_ 16384
#define QK_ 256
#define HEADS_ 8
#define HD_ 32
#define TOPK_ 128
#define NSP_ 256
#define SCALE_F 0.17677669529663687f
#define EPS_ 1e-6f

// ---------------- mean / rstd per pixel ----------------
__global__ __launch_bounds__(256) void k_meanvar(const float* __restrict__ x, float* __restrict__ mu_rstd)
{
    int p = blockIdx.x * 256 + threadIdx.x;          // 0 .. B*HW
    int b = p >> 14, pp = p & (HW_ - 1);
    const float* xb = x + (size_t)b * C_ * HW_ + pp;
    float s = 0.f, s2 = 0.f;
    for (int c = 0; c < C_; c++) {
        float v = xb[(size_t)c * HW_];
        s += v; s2 += v * v;
    }
    float mu = s * (1.f / C_);
    float var = s2 * (1.f / C_) - mu * mu;
    float rstd = rsqrtf(var + EPS_);
    mu_rstd[2 * p] = mu;
    mu_rstd[2 * p + 1] = rstd;
}

// ---------------- fused LN + QKV GEMM (fp32) ----------------
// qkv[b][m][0:256]=q, [256:512]=k, [512:768]=v ; row stride 768
#define GBM 128
#define GBN 128
#define GBK 8
__global__ __launch_bounds__(256) void k_qkv_gemm(
    const float* __restrict__ x, const float* __restrict__ mu_rstd,
    const float* __restrict__ gamma, const float* __restrict__ beta,
    const float* __restrict__ wq, const float* __restrict__ wk, const float* __restrict__ wv,
    float* __restrict__ qkv)
{
    const int b  = blockIdx.z;
    const int m0 = blockIdx.x * GBM;
    const int n0 = blockIdx.y * GBN;
    __shared__ float a_l[GBK][GBM + 4];
    __shared__ float b_l[GBK][GBN + 4];
    __shared__ float g_l[C_], bt_l[C_];
    const int tid = threadIdx.x;
    g_l[tid] = gamma[tid];
    bt_l[tid] = beta[tid];

    const int mm = tid & 127;
    const int kg = tid >> 7;         // 0..1
    const int nn = tid >> 1;         // 0..127
    const int kq = (tid & 1) * 4;    // 0 or 4
    const float2 mr = ((const float2*)mu_rstd)[b * HW_ + m0 + mm];
    const float* xbase = x + (size_t)b * C_ * HW_ + m0 + mm;
    const int n = n0 + nn;
    const float* wrow = (n < 256) ? (wq + (size_t)n * C_)
                     : (n < 512) ? (wk + (size_t)(n - 256) * C_)
                                 : (wv + (size_t)(n - 512) * C_);
    float acc[8][8] = {};
    const int tx = tid & 15, ty = tid >> 4;

    for (int kt = 0; kt < C_; kt += GBK) {
        __syncthreads();
        #pragma unroll
        for (int j = 0; j < 4; j++) {
            int kk = kg + j * 2;
            int c = kt + kk;
            float xv = xbase[(size_t)c * HW_];
            a_l[kk][mm] = (xv - mr.x) * mr.y * g_l[c] + bt_l[c];
        }
        float4 w4 = *(const float4*)(wrow + kt + kq);
        b_l[kq + 0][nn] = w4.x; b_l[kq + 1][nn] = w4.y;
        b_l[kq + 2][nn] = w4.z; b_l[kq + 3][nn] = w4.w;
        __syncthreads();
        #pragma unroll
        for (int kk = 0; kk < GBK; kk++) {
            float4 a0 = *(const float4*)&a_l[kk][ty * 8];
            float4 a1 = *(const float4*)&a_l[kk][ty * 8 + 4];
            float4 b0 = *(const float4*)&b_l[kk][tx * 8];
            float4 b1 = *(const float4*)&b_l[kk][tx * 8 + 4];
            float av[8] = {a0.x,a0.y,a0.z,a0.w,a1.x,a1.y,a1.z,a1.w};
            float bv[8] = {b0.x,b0.y,b0.z,b0.w,b1.x,b1.y,b1.z,b1.w};
            #pragma unroll
            for (int i = 0; i < 8; i++)
                #pragma unroll
                for (int jj = 0; jj < 8; jj++)
                    acc[i][jj] += av[i] * bv[jj];
        }
    }
    float* out0 = qkv + ((size_t)b * HW_ + m0 + ty * 8) * 768 + n0 + tx * 8;
    #pragma unroll
    for (int i = 0; i < 8; i++) {
        *(float4*)(out0 + (size_t)i * 768)     = make_float4(acc[i][0], acc[i][1], acc[i][2], acc[i][3]);
        *(float4*)(out0 + (size_t)i * 768 + 4) = make_float4(acc[i][4], acc[i][5], acc[i][6], acc[i][7]);
    }
}

// ---------------- exact top-128 radix select per row ----------------
__device__ __forceinline__ unsigned fkey(float f)
{
    unsigned u = __float_as_uint(f);
    return (u & 0x80000000u) ? ~u : (u | 0x80000000u);
}

__global__ __launch_bounds__(256) void k_topk(const float* __restrict__ aff,
                                              int* __restrict__ idxo, float* __restrict__ simso)
{
    const int row = blockIdx.x;                  // 0 .. B*NSP
    const float* a = aff + (size_t)row * HW_;
    __shared__ unsigned hist[256];
    __shared__ unsigned sh_prefix;
    __shared__ int sh_need;
    __shared__ unsigned sh_cnt, sh_eq;
    const int tid = threadIdx.x;
    if (tid == 0) { sh_prefix = 0u; sh_need = TOPK_; }

    for (int pass = 0; pass < 4; pass++) {
        hist[tid] = 0u;
        __syncthreads();
        unsigned pref = sh_prefix;
        int sh_amt = 32 - 8 * pass;
        for (int i = tid; i < HW_; i += 256) {
            unsigned key = fkey(a[i]);
            bool cand = (pass == 0) || ((key >> sh_amt) == pref);
            if (cand) atomicAdd(&hist[(key >> (sh_amt - 8)) & 255u], 1u);
        }
        __syncthreads();
        if (tid == 0) {
            unsigned acc = 0; int bsel = 0;
            for (int bin = 255; bin >= 0; bin--) {
                unsigned cg = hist[bin];
                if (acc + cg >= (unsigned)sh_need) { bsel = bin; break; }
                acc += cg;
            }
            sh_prefix = (sh_prefix << 8) | (unsigned)bsel;
            sh_need -= (int)acc;
        }
        __syncthreads();
    }
    const unsigned T = sh_prefix;
    const int e_take = sh_need;          // how many equal-to-T to take (>=1)
    if (tid == 0) { sh_cnt = 0u; sh_eq = 0u; }
    __syncthreads();
    int* orow = idxo + (size_t)row * TOPK_;
    float* srow = simso + (size_t)row * TOPK_;
    for (int i = tid; i < HW_; i += 256) {
        float v = a[i];
        unsigned key = fkey(v);
        if (key > T) {
            unsigned slot = atomicAdd(&sh_cnt, 1u);
            orow[slot] = i; srow[slot] = v;
        } else if (key == T) {
            atomicAdd(&sh_eq, 1u);
        }
    }
    __syncthreads();
    const unsigned G = sh_cnt;
    const unsigned E = sh_eq;
    if ((int)E == e_take) {
        for (int i = tid; i < HW_; i += 256) {
            float v = a[i];
            if (fkey(v) == T) {
                unsigned slot = atomicAdd(&sh_cnt, 1u);
                orow[slot] = i; srow[slot] = v;
            }
        }
    } else if (tid == 0) {
        // rare tie at boundary: take equals with smallest indices (JAX tie-break)
        unsigned slot = G; int taken = 0;
        for (int i = 0; i < HW_ && taken < e_take; i++) {
            float v = a[i];
            if (fkey(v) == T) { orow[slot] = i; srow[slot] = v; slot++; taken++; }
        }
    }
}

// ---------------- attention + scatter ----------------
template <bool TMP>
__global__ __launch_bounds__(128) void k_attn(
    const float* __restrict__ qkv, const int* __restrict__ idxb,
    const float* __restrict__ sims, float* __restrict__ dst)
{
    const int sp = blockIdx.x, h = blockIdx.y, b = blockIdx.z;
    __shared__ float k_l[TOPK_][HD_];
    __shared__ float vw_l[TOPK_][HD_];
    __shared__ float sims_l[TOPK_];
    __shared__ int idx_l[TOPK_];
    const int tid = threadIdx.x;
    const int roff = (b * NSP_ + sp) * TOPK_;
    idx_l[tid] = idxb[roff + tid];
    sims_l[tid] = sims[roff + tid];
    __syncthreads();
    const float* base = qkv + (size_t)b * HW_ * 768;
    #pragma unroll
    for (int it = 0; it < 8; it++) {
        int flat = it * 128 + tid;
        int s = flat >> 3, c4 = (flat & 7) * 4;
        const float* krow = base + (size_t)idx_l[s] * 768 + 256 + h * HD_ + c4;
        *(float4*)&k_l[s][c4] = *(const float4*)krow;
        const float* vrow = base + (size_t)idx_l[s] * 768 + 512 + h * HD_ + c4;
        float4 vv = *(const float4*)vrow;
        float wgt = sims_l[s];
        *(float4*)&vw_l[s][c4] = make_float4(vv.x * wgt, vv.y * wgt, vv.z * wgt, vv.w * wgt);
    }
    float q[HD_];
    const int pix = idx_l[tid];
    const float* qrow = base + (size_t)pix * 768 + h * HD_;
    #pragma unroll
    for (int j = 0; j < 8; j++) {
        float4 t4 = *(const float4*)(qrow + j * 4);
        q[j*4] = t4.x; q[j*4+1] = t4.y; q[j*4+2] = t4.z; q[j*4+3] = t4.w;
    }
    __syncthreads();
    float m = -1e30f, l = 0.f, acc[HD_];
    #pragma unroll
    for (int c = 0; c < HD_; c++) acc[c] = 0.f;
    for (int s = 0; s < TOPK_; s++) {
        float d = 0.f;
        #pragma unroll
        for (int c4 = 0; c4 < 8; c4++) {
            float4 kk4 = *(const float4*)&k_l[s][c4 * 4];
            d += q[c4*4]*kk4.x + q[c4*4+1]*kk4.y + q[c4*4+2]*kk4.z + q[c4*4+3]*kk4.w;
        }
        d *= SCALE_F;
        float mn = fmaxf(m, d);
        float fac = __expf(m - mn);
        float p = __expf(d - mn);
        l = l * fac + p;
        #pragma unroll
        for (int c4 = 0; c4 < 8; c4++) {
            float4 vv4 = *(const float4*)&vw_l[s][c4 * 4];
            acc[c4*4]   = acc[c4*4]   * fac + p * vv4.x;
            acc[c4*4+1] = acc[c4*4+1] * fac + p * vv4.y;
            acc[c4*4+2] = acc[c4*4+2] * fac + p * vv4.z;
            acc[c4*4+3] = acc[c4*4+3] * fac + p * vv4.w;
        }
        m = mn;
    }
    const float wt = sims_l[tid] / l;
    if (TMP) {
        float* drow = dst + ((size_t)(b * HW_) + pix) * C_ + h * HD_;
        #pragma unroll
        for (int c = 0; c < HD_; c++) atomicAdd(&drow[c], acc[c] * wt);
    } else {
        float* dbase = dst + ((size_t)b * C_ + h * HD_) * HW_ + pix;
        #pragma unroll
        for (int c = 0; c < HD_; c++) atomicAdd(dbase + (size_t)c * HW_, acc[c] * wt);
    }
}

// ---------------- final: out[b][c][p] = v[b][p][c] (+ tmp[b][p][c]) ----------------
__global__ __launch_bounds__(256) void k_final(const float* __restrict__ qkv,
                                               const float* __restrict__ tmp, float* __restrict__ out)
{
    const int b = blockIdx.z;
    const int p0 = blockIdx.x * 64, c0 = blockIdx.y * 64;
    __shared__ float t[64][65];
    const int tid = threadIdx.x;
    #pragma unroll
    for (int it = 0; it < 16; it++) {
        int flat = it * 256 + tid;
        int r = flat >> 6, cc = flat & 63;
        float v = qkv[((size_t)b * HW_ + p0 + r) * 768 + 512 + c0 + cc]
                + tmp[((size_t)b * HW_ + p0 + r) * C_ + c0 + cc];
        t[r][cc] = v;
    }
    __syncthreads();
    #pragma unroll
    for (int it = 0; it < 16; it++) {
        int flat = it * 256 + tid;
        int rr = flat >> 6, pp = flat & 63;
        out[((size_t)b * C_ + c0 + rr) * HW_ + p0 + pp] = t[pp][rr];
    }
}

__global__ __launch_bounds__(256) void k_vinit(const float* __restrict__ qkv, float* __restrict__ out)
{
    const int b = blockIdx.z;
    const int p0 = blockIdx.x * 64, c0 = blockIdx.y * 64;
    __shared__ float t[64][65];
    const int tid = threadIdx.x;
    #pragma unroll
    for (int it = 0; it < 16; it++) {
        int flat = it * 256 + tid;
        int r = flat >> 6, cc = flat & 63;
        t[r][cc] = qkv[((size_t)b * HW_ + p0 + r) * 768 + 512 + c0 + cc];
    }
    __syncthreads();
    #pragma unroll
    for (int it = 0; it < 16; it++) {
        int flat = it * 256 + tid;
        int rr = flat >> 6, pp = flat & 63;
        out[((size_t)b * C_ + c0 + rr) * HW_ + p0 + pp] = t[pp][rr];
    }
}

extern "C" void kernel_launch(void* const* d_in, const int* in_sizes, int n_in,
                              void* d_out, int out_size, void* d_ws, size_t ws_size,
                              hipStream_t stream)
{
    (void)in_sizes; (void)n_in; (void)out_size;
    const float* x     = (const float*)d_in[0];
    const float* aff   = (const float*)d_in[1];
    const float* gamma = (const float*)d_in[2];
    const float* beta  = (const float*)d_in[3];
    const float* wq    = (const float*)d_in[4];
    const float* wk    = (const float*)d_in[5];
    const float* wv    = (const float*)d_in[6];
    float* out = (float*)d_out;
    float* ws  = (float*)d_ws;

    const size_t n_mu   = (size_t)2 * B_ * HW_;          // 65536
    const size_t n_qkv  = (size_t)B_ * HW_ * 768;        // 25165824
    const size_t n_idx  = (size_t)B_ * NSP_ * TOPK_;     // 65536
    const size_t n_tmp  = (size_t)B_ * HW_ * C_;         // 8388608

    float* mu_rstd = ws;
    float* qkv     = ws + n_mu;
    int*   idxb    = (int*)(ws + n_mu + n_qkv);
    float* sims    = ws + n_mu + n_qkv + n_idx;
    float* tmp     = ws + n_mu + n_qkv + 2 * n_idx;
    const size_t need_tmp_bytes = (n_mu + n_qkv + 2 * n_idx + n_tmp) * 4;
    const bool use_tmp = ws_size >= need_tmp_bytes;

    k_meanvar<<<dim3((B_ * HW_) / 256), 256, 0, stream>>>(x, mu_rstd);

    dim3 gg(HW_ / GBM, 768 / GBN, B_);
    k_qkv_gemm<<<gg, 256, 0, stream>>>(x, mu_rstd, gamma, beta, wq, wk, wv, qkv);

    k_topk<<<dim3(B_ * NSP_), 256, 0, stream>>>(aff, idxb, sims);

    if (use_tmp) {
        hipMemsetAsync(tmp, 0, n_tmp * 4, stream);
        dim3 ga(NSP_, HEADS_, B_);
        k_attn<true><<<ga, 128, 0, stream>>>(qkv, idxb, sims, tmp);
        dim3 gf(HW_ / 64, C_ / 64, B_);
        k_final<<<gf, 256, 0, stream>>>(qkv, tmp, out);
    } else {
        dim3 gf(HW_ / 64, C_ / 64, B_);
        k_vinit<<<gf, 256, 0, stream>>>(qkv, out);
        dim3 ga(NSP_, HEADS_, B_);
        k_attn<false><<<ga, 128, 0, stream>>>(qkv, idxb, sims, out);
    }
}

// Round 3
// 1406.454 us; speedup vs baseline: 1.3481x; 1.3481x over previous
//
#include <hip/hip_runtime.h>
#include <hip/hip_bf16.h>

#define B_ 2
#define C_ 256
#define H_ 128
#define W_ 128
#define HW_ 16384
#define QK_ 256
#define HEADS_ 8
#define HD_ 32
#define TOPK_ 128
#define NSP_ 256
#define SCALE_F 0.17677669529663687f
#define EPS_ 1e-6f

typedef __attribute__((ext_vector_type(16))) float f32x16;
typedef __attribute__((ext_vector_type(8))) short bf16x8;
typedef unsigned short ushort_t;
union FragU { unsigned int u[4]; bf16x8 v; };

// manual f32 -> bf16 (round-to-nearest-even), pure VALU, no asm
__device__ __forceinline__ ushort_t f2bf(float x)
{
    unsigned u = __float_as_uint(x);
    return (ushort_t)((u + 0x7fffu + ((u >> 16) & 1u)) >> 16);
}
__device__ __forceinline__ unsigned pk2(float a, float b)
{
    return (unsigned)f2bf(a) | ((unsigned)f2bf(b) << 16);
}

// split 8 f32 into bf16 hi + bf16 residual fragments (3-mfma fp32 emulation)
__device__ __forceinline__ void split8(const float* f, FragU& hi, FragU& lo)
{
    #pragma unroll
    for (int j = 0; j < 4; j++) {
        ushort_t h0 = f2bf(f[2*j]);
        ushort_t h1 = f2bf(f[2*j+1]);
        hi.u[j] = (unsigned)h0 | ((unsigned)h1 << 16);
        float hf0 = __uint_as_float((unsigned)h0 << 16);
        float hf1 = __uint_as_float((unsigned)h1 << 16);
        lo.u[j] = pk2(f[2*j] - hf0, f[2*j+1] - hf1);
    }
}

// ---------------- mean / rstd per pixel ----------------
__global__ __launch_bounds__(256) void k_meanvar(const float* __restrict__ x, float* __restrict__ mu_rstd)
{
    int p = blockIdx.x * 256 + threadIdx.x;          // 0 .. B*HW
    int b = p >> 14, pp = p & (HW_ - 1);
    const float* xb = x + (size_t)b * C_ * HW_ + pp;
    float s = 0.f, s2 = 0.f;
    for (int c = 0; c < C_; c++) {
        float v = xb[(size_t)c * HW_];
        s += v; s2 += v * v;
    }
    float mu = s * (1.f / C_);
    float var = s2 * (1.f / C_) - mu * mu;
    float rstd = rsqrtf(var + EPS_);
    mu_rstd[2 * p] = mu;
    mu_rstd[2 * p + 1] = rstd;
}

// ---------------- fused LN + QKV GEMM (fp32) ----------------
#define GBM 128
#define GBN 128
#define GBK 8
__global__ __launch_bounds__(256) void k_qkv_gemm(
    const float* __restrict__ x, const float* __restrict__ mu_rstd,
    const float* __restrict__ gamma, const float* __restrict__ beta,
    const float* __restrict__ wq, const float* __restrict__ wk, const float* __restrict__ wv,
    float* __restrict__ qkv)
{
    const int b  = blockIdx.z;
    const int m0 = blockIdx.x * GBM;
    const int n0 = blockIdx.y * GBN;
    __shared__ float a_l[GBK][GBM + 4];
    __shared__ float b_l[GBK][GBN + 4];
    __shared__ float g_l[C_], bt_l[C_];
    const int tid = threadIdx.x;
    g_l[tid] = gamma[tid];
    bt_l[tid] = beta[tid];

    const int mm = tid & 127;
    const int kg = tid >> 7;
    const int nn = tid >> 1;
    const int kq = (tid & 1) * 4;
    const float2 mr = ((const float2*)mu_rstd)[b * HW_ + m0 + mm];
    const float* xbase = x + (size_t)b * C_ * HW_ + m0 + mm;
    const int n = n0 + nn;
    const float* wrow = (n < 256) ? (wq + (size_t)n * C_)
                     : (n < 512) ? (wk + (size_t)(n - 256) * C_)
                                 : (wv + (size_t)(n - 512) * C_);
    float acc[8][8] = {};
    const int tx = tid & 15, ty = tid >> 4;

    for (int kt = 0; kt < C_; kt += GBK) {
        __syncthreads();
        #pragma unroll
        for (int j = 0; j < 4; j++) {
            int kk = kg + j * 2;
            int c = kt + kk;
            float xv = xbase[(size_t)c * HW_];
            a_l[kk][mm] = (xv - mr.x) * mr.y * g_l[c] + bt_l[c];
        }
        float4 w4 = *(const float4*)(wrow + kt + kq);
        b_l[kq + 0][nn] = w4.x; b_l[kq + 1][nn] = w4.y;
        b_l[kq + 2][nn] = w4.z; b_l[kq + 3][nn] = w4.w;
        __syncthreads();
        #pragma unroll
        for (int kk = 0; kk < GBK; kk++) {
            float4 a0 = *(const float4*)&a_l[kk][ty * 8];
            float4 a1 = *(const float4*)&a_l[kk][ty * 8 + 4];
            float4 b0 = *(const float4*)&b_l[kk][tx * 8];
            float4 b1 = *(const float4*)&b_l[kk][tx * 8 + 4];
            float av[8] = {a0.x,a0.y,a0.z,a0.w,a1.x,a1.y,a1.z,a1.w};
            float bv[8] = {b0.x,b0.y,b0.z,b0.w,b1.x,b1.y,b1.z,b1.w};
            #pragma unroll
            for (int i = 0; i < 8; i++)
                #pragma unroll
                for (int jj = 0; jj < 8; jj++)
                    acc[i][jj] += av[i] * bv[jj];
        }
    }
    float* out0 = qkv + ((size_t)b * HW_ + m0 + ty * 8) * 768 + n0 + tx * 8;
    #pragma unroll
    for (int i = 0; i < 8; i++) {
        *(float4*)(out0 + (size_t)i * 768)     = make_float4(acc[i][0], acc[i][1], acc[i][2], acc[i][3]);
        *(float4*)(out0 + (size_t)i * 768 + 4) = make_float4(acc[i][4], acc[i][5], acc[i][6], acc[i][7]);
    }
}

// ---------------- exact top-128 radix select per row ----------------
__device__ __forceinline__ unsigned fkey(float f)
{
    unsigned u = __float_as_uint(f);
    return (u & 0x80000000u) ? ~u : (u | 0x80000000u);
}

__global__ __launch_bounds__(256) void k_topk(const float* __restrict__ aff,
                                              int* __restrict__ idxo, float* __restrict__ simso)
{
    const int row = blockIdx.x;
    const float* a = aff + (size_t)row * HW_;
    __shared__ unsigned hist[256];
    __shared__ unsigned sh_prefix;
    __shared__ int sh_need;
    __shared__ unsigned sh_cnt, sh_eq;
    const int tid = threadIdx.x;
    if (tid == 0) { sh_prefix = 0u; sh_need = TOPK_; }

    for (int pass = 0; pass < 4; pass++) {
        hist[tid] = 0u;
        __syncthreads();
        unsigned pref = sh_prefix;
        int sh_amt = 32 - 8 * pass;
        for (int i = tid; i < HW_; i += 256) {
            unsigned key = fkey(a[i]);
            bool cand = (pass == 0) || ((key >> sh_amt) == pref);
            if (cand) atomicAdd(&hist[(key >> (sh_amt - 8)) & 255u], 1u);
        }
        __syncthreads();
        if (tid == 0) {
            unsigned acc = 0; int bsel = 0;
            for (int bin = 255; bin >= 0; bin--) {
                unsigned cg = hist[bin];
                if (acc + cg >= (unsigned)sh_need) { bsel = bin; break; }
                acc += cg;
            }
            sh_prefix = (sh_prefix << 8) | (unsigned)bsel;
            sh_need -= (int)acc;
        }
        __syncthreads();
    }
    const unsigned T = sh_prefix;
    const int e_take = sh_need;
    if (tid == 0) { sh_cnt = 0u; sh_eq = 0u; }
    __syncthreads();
    int* orow = idxo + (size_t)row * TOPK_;
    float* srow = simso + (size_t)row * TOPK_;
    for (int i = tid; i < HW_; i += 256) {
        float v = a[i];
        unsigned key = fkey(v);
        if (key > T) {
            unsigned slot = atomicAdd(&sh_cnt, 1u);
            orow[slot] = i; srow[slot] = v;
        } else if (key == T) {
            atomicAdd(&sh_eq, 1u);
        }
    }
    __syncthreads();
    const unsigned G = sh_cnt;
    const unsigned E = sh_eq;
    if ((int)E == e_take) {
        for (int i = tid; i < HW_; i += 256) {
            float v = a[i];
            if (fkey(v) == T) {
                unsigned slot = atomicAdd(&sh_cnt, 1u);
                orow[slot] = i; srow[slot] = v;
            }
        }
    } else if (tid == 0) {
        unsigned slot = G; int taken = 0;
        for (int i = 0; i < HW_ && taken < e_take; i++) {
            float v = a[i];
            if (fkey(v) == T) { orow[slot] = i; srow[slot] = v; slot++; taken++; }
        }
    }
}

// ---------------- MFMA attention (swapped QK^T, in-register softmax) ----------------
// block = 256 threads = 4 waves; wave w owns q-rows [32w,32w+32)
// S^T tile: D[r=s][c=q] via mfma(A=K, B=Q^T); bf16 hi/lo split => fp32-accurate scores.
// PV: O^T[c][q] = mfma(A=V^T (LDS, bf16, sims-weighted), B=P^T hi/lo via lane^32 exchange).
__global__ __launch_bounds__(256) void k_attn_mfma(
    const float* __restrict__ qkv, const int* __restrict__ idxb,
    const float* __restrict__ sims, float* __restrict__ tmp)
{
    const int sp = blockIdx.x, h = blockIdx.y, b = blockIdx.z;
    __shared__ int idx_l[TOPK_];
    __shared__ float sims_l[TOPK_];
    __shared__ __align__(16) ushort_t vt[HD_][TOPK_ + 8];

    const int tid = threadIdx.x;
    const int roff = (b * NSP_ + sp) * TOPK_;
    if (tid < TOPK_) {
        idx_l[tid] = idxb[roff + tid];
        sims_l[tid] = sims[roff + tid];
    }
    __syncthreads();

    const float* qb = qkv + (size_t)b * HW_ * 768;

    // stage sims-weighted V^T into LDS (bf16)
    {
        const int s = tid >> 1, ch = (tid & 1) * 16;
        const float wgt = sims_l[s];
        const float* vrow = qb + (size_t)idx_l[s] * 768 + 512 + h * HD_ + ch;
        #pragma unroll
        for (int j4 = 0; j4 < 4; j4++) {
            float4 vv = *(const float4*)(vrow + j4 * 4);
            vt[ch + j4 * 4 + 0][s] = f2bf(vv.x * wgt);
            vt[ch + j4 * 4 + 1][s] = f2bf(vv.y * wgt);
            vt[ch + j4 * 4 + 2][s] = f2bf(vv.z * wgt);
            vt[ch + j4 * 4 + 3][s] = f2bf(vv.w * wgt);
        }
    }

    const int lane = tid & 63, w = tid >> 6;
    const int lq = lane & 31, hi = lane >> 5;
    const int qrow = idx_l[w * 32 + lq];

    f32x16 sacc[4];
    #pragma unroll
    for (int s = 0; s < 4; s++)
        #pragma unroll
        for (int r = 0; r < 16; r++) sacc[s][r] = 0.f;

    // QK^T: A = K rows (gathered direct from global), B = Q^T cols
    #pragma unroll
    for (int t = 0; t < 2; t++) {
        const float* qp = qb + (size_t)qrow * 768 + h * HD_ + t * 16 + hi * 8;
        float q8[8];
        {
            float4 t0 = *(const float4*)qp;
            float4 t1 = *(const float4*)(qp + 4);
            q8[0]=t0.x; q8[1]=t0.y; q8[2]=t0.z; q8[3]=t0.w;
            q8[4]=t1.x; q8[5]=t1.y; q8[6]=t1.z; q8[7]=t1.w;
        }
        FragU qh, ql; split8(q8, qh, ql);
        #pragma unroll
        for (int s = 0; s < 4; s++) {
            const int krow = idx_l[s * 32 + lq];
            const float* kp = qb + (size_t)krow * 768 + 256 + h * HD_ + t * 16 + hi * 8;
            float k8[8];
            {
                float4 t0 = *(const float4*)kp;
                float4 t1 = *(const float4*)(kp + 4);
                k8[0]=t0.x; k8[1]=t0.y; k8[2]=t0.z; k8[3]=t0.w;
                k8[4]=t1.x; k8[5]=t1.y; k8[6]=t1.z; k8[7]=t1.w;
            }
            FragU kh, kl; split8(k8, kh, kl);
            sacc[s] = __builtin_amdgcn_mfma_f32_32x32x16_bf16(kh.v, qh.v, sacc[s], 0, 0, 0);
            sacc[s] = __builtin_amdgcn_mfma_f32_32x32x16_bf16(kh.v, ql.v, sacc[s], 0, 0, 0);
            sacc[s] = __builtin_amdgcn_mfma_f32_32x32x16_bf16(kl.v, qh.v, sacc[s], 0, 0, 0);
        }
    }

    // full softmax over s: lane holds 64 of the 128 s-values for its q; other 64 in lane^32
    float m = -1e30f;
    #pragma unroll
    for (int s = 0; s < 4; s++)
        #pragma unroll
        for (int r = 0; r < 16; r++) m = fmaxf(m, sacc[s][r]);
    m = fmaxf(m, __shfl_xor(m, 32));
    float lsum = 0.f;
    #pragma unroll
    for (int s = 0; s < 4; s++)
        #pragma unroll
        for (int r = 0; r < 16; r++) {
            float p = __expf((sacc[s][r] - m) * SCALE_F);
            sacc[s][r] = p;
            lsum += p;
        }
    lsum += __shfl_xor(lsum, 32);

    __syncthreads();   // vt ready

    f32x16 oacc;
    #pragma unroll
    for (int r = 0; r < 16; r++) oacc[r] = 0.f;

    #pragma unroll
    for (int t = 0; t < 8; t++) {
        const int st = t >> 1, rb = (t & 1) * 8;
        unsigned A0 = pk2(sacc[st][rb + 0], sacc[st][rb + 1]);
        unsigned A1 = pk2(sacc[st][rb + 2], sacc[st][rb + 3]);
        unsigned B0 = pk2(sacc[st][rb + 4], sacc[st][rb + 5]);
        unsigned B1 = pk2(sacc[st][rb + 6], sacc[st][rb + 7]);
        unsigned sA0 = (unsigned)__shfl_xor((int)A0, 32);
        unsigned sA1 = (unsigned)__shfl_xor((int)A1, 32);
        unsigned sB0 = (unsigned)__shfl_xor((int)B0, 32);
        unsigned sB1 = (unsigned)__shfl_xor((int)B1, 32);
        FragU pf;
        pf.u[0] = hi ? sB0 : A0;
        pf.u[1] = hi ? sB1 : A1;
        pf.u[2] = hi ? B0 : sA0;
        pf.u[3] = hi ? B1 : sA1;
        bf16x8 vf = *(const bf16x8*)&vt[lq][t * 16 + hi * 8];
        oacc = __builtin_amdgcn_mfma_f32_32x32x16_bf16(vf, pf.v, oacc, 0, 0, 0);
    }

    const float wt = sims_l[w * 32 + lq] / lsum;
    float* drow = tmp + ((size_t)(b * HW_) + qrow) * C_ + h * HD_;
    #pragma unroll
    for (int r = 0; r < 16; r++) {
        int c = (r & 3) + 8 * (r >> 2) + 4 * hi;
        atomicAdd(&drow[c], oacc[r] * wt);
    }
}

// ---------------- fallback attention (strided atomics straight to out) ----------------
__global__ __launch_bounds__(128) void k_attn_fb(
    const float* __restrict__ qkv, const int* __restrict__ idxb,
    const float* __restrict__ sims, float* __restrict__ dst)
{
    const int sp = blockIdx.x, h = blockIdx.y, b = blockIdx.z;
    __shared__ float k_l[TOPK_][HD_];
    __shared__ float vw_l[TOPK_][HD_];
    __shared__ float sims_l[TOPK_];
    __shared__ int idx_l[TOPK_];
    const int tid = threadIdx.x;
    const int roff = (b * NSP_ + sp) * TOPK_;
    idx_l[tid] = idxb[roff + tid];
    sims_l[tid] = sims[roff + tid];
    __syncthreads();
    const float* base = qkv + (size_t)b * HW_ * 768;
    #pragma unroll
    for (int it = 0; it < 8; it++) {
        int flat = it * 128 + tid;
        int s = flat >> 3, c4 = (flat & 7) * 4;
        const float* krow = base + (size_t)idx_l[s] * 768 + 256 + h * HD_ + c4;
        *(float4*)&k_l[s][c4] = *(const float4*)krow;
        const float* vrow = base + (size_t)idx_l[s] * 768 + 512 + h * HD_ + c4;
        float4 vv = *(const float4*)vrow;
        float wgt = sims_l[s];
        *(float4*)&vw_l[s][c4] = make_float4(vv.x * wgt, vv.y * wgt, vv.z * wgt, vv.w * wgt);
    }
    float q[HD_];
    const int pix = idx_l[tid];
    const float* qrow = base + (size_t)pix * 768 + h * HD_;
    #pragma unroll
    for (int j = 0; j < 8; j++) {
        float4 t4 = *(const float4*)(qrow + j * 4);
        q[j*4] = t4.x; q[j*4+1] = t4.y; q[j*4+2] = t4.z; q[j*4+3] = t4.w;
    }
    __syncthreads();
    float m = -1e30f, l = 0.f, acc[HD_];
    #pragma unroll
    for (int c = 0; c < HD_; c++) acc[c] = 0.f;
    for (int s = 0; s < TOPK_; s++) {
        float d = 0.f;
        #pragma unroll
        for (int c4 = 0; c4 < 8; c4++) {
            float4 kk4 = *(const float4*)&k_l[s][c4 * 4];
            d += q[c4*4]*kk4.x + q[c4*4+1]*kk4.y + q[c4*4+2]*kk4.z + q[c4*4+3]*kk4.w;
        }
        d *= SCALE_F;
        float mn = fmaxf(m, d);
        float fac = __expf(m - mn);
        float p = __expf(d - mn);
        l = l * fac + p;
        #pragma unroll
        for (int c4 = 0; c4 < 8; c4++) {
            float4 vv4 = *(const float4*)&vw_l[s][c4 * 4];
            acc[c4*4]   = acc[c4*4]   * fac + p * vv4.x;
            acc[c4*4+1] = acc[c4*4+1] * fac + p * vv4.y;
            acc[c4*4+2] = acc[c4*4+2] * fac + p * vv4.z;
            acc[c4*4+3] = acc[c4*4+3] * fac + p * vv4.w;
        }
        m = mn;
    }
    const float wt = sims_l[tid] / l;
    float* dbase = dst + ((size_t)b * C_ + h * HD_) * HW_ + pix;
    #pragma unroll
    for (int c = 0; c < HD_; c++) atomicAdd(dbase + (size_t)c * HW_, acc[c] * wt);
}

// ---------------- final: out[b][c][p] = v[b][p][c] (+ tmp[b][p][c]) ----------------
__global__ __launch_bounds__(256) void k_final(const float* __restrict__ qkv,
                                               const float* __restrict__ tmp, float* __restrict__ out)
{
    const int b = blockIdx.z;
    const int p0 = blockIdx.x * 64, c0 = blockIdx.y * 64;
    __shared__ float t[64][65];
    const int tid = threadIdx.x;
    #pragma unroll
    for (int it = 0; it < 16; it++) {
        int flat = it * 256 + tid;
        int r = flat >> 6, cc = flat & 63;
        float v = qkv[((size_t)b * HW_ + p0 + r) * 768 + 512 + c0 + cc]
                + tmp[((size_t)b * HW_ + p0 + r) * C_ + c0 + cc];
        t[r][cc] = v;
    }
    __syncthreads();
    #pragma unroll
    for (int it = 0; it < 16; it++) {
        int flat = it * 256 + tid;
        int rr = flat >> 6, pp = flat & 63;
        out[((size_t)b * C_ + c0 + rr) * HW_ + p0 + pp] = t[pp][rr];
    }
}

__global__ __launch_bounds__(256) void k_vinit(const float* __restrict__ qkv, float* __restrict__ out)
{
    const int b = blockIdx.z;
    const int p0 = blockIdx.x * 64, c0 = blockIdx.y * 64;
    __shared__ float t[64][65];
    const int tid = threadIdx.x;
    #pragma unroll
    for (int it = 0; it < 16; it++) {
        int flat = it * 256 + tid;
        int r = flat >> 6, cc = flat & 63;
        t[r][cc] = qkv[((size_t)b * HW_ + p0 + r) * 768 + 512 + c0 + cc];
    }
    __syncthreads();
    #pragma unroll
    for (int it = 0; it < 16; it++) {
        int flat = it * 256 + tid;
        int rr = flat >> 6, pp = flat & 63;
        out[((size_t)b * C_ + c0 + rr) * HW_ + p0 + pp] = t[pp][rr];
    }
}

extern "C" void kernel_launch(void* const* d_in, const int* in_sizes, int n_in,
                              void* d_out, int out_size, void* d_ws, size_t ws_size,
                              hipStream_t stream)
{
    (void)in_sizes; (void)n_in; (void)out_size;
    const float* x     = (const float*)d_in[0];
    const float* aff   = (const float*)d_in[1];
    const float* gamma = (const float*)d_in[2];
    const float* beta  = (const float*)d_in[3];
    const float* wq    = (const float*)d_in[4];
    const float* wk    = (const float*)d_in[5];
    const float* wv    = (const float*)d_in[6];
    float* out = (float*)d_out;
    float* ws  = (float*)d_ws;

    const size_t n_mu   = (size_t)2 * B_ * HW_;
    const size_t n_qkv  = (size_t)B_ * HW_ * 768;
    const size_t n_idx  = (size_t)B_ * NSP_ * TOPK_;
    const size_t n_tmp  = (size_t)B_ * HW_ * C_;

    float* mu_rstd = ws;
    float* qkv     = ws + n_mu;
    int*   idxb    = (int*)(ws + n_mu + n_qkv);
    float* sims    = ws + n_mu + n_qkv + n_idx;
    float* tmp     = ws + n_mu + n_qkv + 2 * n_idx;
    const size_t need_tmp_bytes = (n_mu + n_qkv + 2 * n_idx + n_tmp) * 4;
    const bool use_tmp = ws_size >= need_tmp_bytes;

    k_meanvar<<<dim3((B_ * HW_) / 256), 256, 0, stream>>>(x, mu_rstd);

    dim3 gg(HW_ / GBM, 768 / GBN, B_);
    k_qkv_gemm<<<gg, 256, 0, stream>>>(x, mu_rstd, gamma, beta, wq, wk, wv, qkv);

    k_topk<<<dim3(B_ * NSP_), 256, 0, stream>>>(aff, idxb, sims);

    if (use_tmp) {
        hipMemsetAsync(tmp, 0, n_tmp * 4, stream);
        dim3 ga(NSP_, HEADS_, B_);
        k_attn_mfma<<<ga, 256, 0, stream>>>(qkv, idxb, sims, tmp);
        dim3 gf(HW_ / 64, C_ / 64, B_);
        k_final<<<gf, 256, 0, stream>>>(qkv, tmp, out);
    } else {
        dim3 gf(HW_ / 64, C_ / 64, B_);
        k_vinit<<<gf, 256, 0, stream>>>(qkv, out);
        dim3 ga(NSP_, HEADS_, B_);
        k_attn_fb<<<ga, 128, 0, stream>>>(qkv, idxb, sims, out);
    }
}